// Round 6
// baseline (1218.653 us; speedup 1.0000x reference)
//
#include <hip/hip_runtime.h>

#define NPTS 80000
#define MPTS 150000
#define NDPTS 10000
#define KOFF 27
#define C3 16
#define CP 259
#define C2 64
#define CM 80
#define CO 96

typedef __attribute__((ext_vector_type(8))) short short8;
typedef __attribute__((ext_vector_type(4))) short s16x4;
typedef __attribute__((ext_vector_type(4))) float f32x4;

__device__ inline short bf16r(float f) {
  union { float f; unsigned u; } x{f};
  unsigned r = (x.u + 0x7fffu + ((x.u >> 16) & 1u)) >> 16;
  return (short)r;
}

// ---------------------------------------------------------------------------
// Weight prep: W[k][ci][n] fp32 -> fragment-ordered bf16
// WbfF[((k*KC+q)*NT+t)*512 + lane*8 + j]; ci = q*32+(lane>>4)*8+j,
// n = t*16+(lane&15); ci >= CIN zero-padded.
// ---------------------------------------------------------------------------
__global__ void wfrag_kernel(const float* __restrict__ W, short* __restrict__ WbfF,
                             int CIN, int COUT_, int KC) {
  const int NT = COUT_ / 16;
  int i = blockIdx.x * 256 + threadIdx.x;
  int total = KOFF * KC * NT * 512;
  if (i >= total) return;
  int j = i & 7, lane = (i >> 3) & 63;
  int rest = i >> 9;
  int t = rest % NT; rest /= NT;
  int q = rest % KC;
  int k = rest / KC;
  int ci = q * 32 + (lane >> 4) * 8 + j;
  int n = t * 16 + (lane & 15);
  float v = (ci < CIN) ? W[((size_t)k * CIN + ci) * COUT_ + n] : 0.f;
  WbfF[i] = bf16r(v);
}

// Wp prep: fp32 [259][64] -> bf16 fragment-ordered [q][t][lane][8], K->288.
__global__ void wpfrag_kernel(const float* __restrict__ Wp, short* __restrict__ WpF) {
  int i = blockIdx.x * 256 + threadIdx.x;
  if (i >= 9 * 4 * 64 * 8) return;
  int j = i & 7, lane = (i >> 3) & 63, t = (i >> 9) & 3, q = i >> 11;
  int k = q * 32 + (lane >> 4) * 8 + j;
  int n = t * 16 + (lane & 15);
  WpF[i] = (k < CP) ? bf16r(Wp[(size_t)k * C2 + n]) : (short)0;
}

// W3d prep: [27][16][16] fp32 -> fragment-ordered bf16 over packed K=27*16
// (pad 448 = 14 chunks). W3dF[q*512 + lane*8 + j]: kci = q*32+(lane>>4)*8+j,
// offset o = kci>>4, ci = kci&15, n = lane&15.
__global__ void w3dfrag_kernel(const float* __restrict__ W3d, short* __restrict__ W3dF) {
  int i = blockIdx.x * 256 + threadIdx.x;
  if (i >= 14 * 512) return;
  int j = i & 7, lane = (i >> 3) & 63, q = i >> 9;
  int kci = q * 32 + (lane >> 4) * 8 + j;
  int o = kci >> 4, ci = kci & 15, n = lane & 15;
  W3dF[i] = (o < KOFF) ? bf16r(W3d[((size_t)o * C3 + ci) * C3 + n]) : (short)0;
}

// x3d fp32 -> bf16
__global__ void x3dprep_kernel(const float* __restrict__ x3d, short* __restrict__ x3dbf) {
  int i = blockIdx.x * 256 + threadIdx.x;
  if (i < NPTS * C3) x3dbf[i] = bf16r(x3d[i]);
}

// ---------------------------------------------------------------------------
// conv3d as MFMA: packed K = 27 offsets x 16 ch (14 chunks of 32). Per chunk
// iteration: stage 128 rows x 32 cols (2 offsets) into double-buffered LDS
// with 8B coalesced gathers from L2-resident x3dbf; 1 barrier/chunk;
// dist-1 register prefetch. Epilogue: bn_relu -> y3d fp32 + mix + mixbf.
// ---------------------------------------------------------------------------
__global__ __launch_bounds__(256, 4) void conv3d_mfma_kernel(
    const short* __restrict__ x3dbf, const int* __restrict__ nbr,
    const short* __restrict__ W3dF, const float* __restrict__ g3d,
    const float* __restrict__ b3d, float* __restrict__ y3d,
    float* __restrict__ mix, short* __restrict__ mixbf)
{
  constexpr int QCH = 14;
  constexpr int AS3 = 40;                 // LDS row stride (shorts)
  __shared__ short fA[2][128 * AS3];
  const int tid = threadIdx.x;
  const int lane = tid & 63;
  const int w = tid >> 6;
  const int lm = lane & 15;
  const int quad = lane >> 4;
  const int base = blockIdx.x * 128;

  int srow[4], sc[4];
  #pragma unroll
  for (int i = 0; i < 4; ++i) {
    int j = tid + i * 256;
    srow[i] = j >> 3;
    sc[i] = j & 7;
  }

  f32x4 acc[2];
  #pragma unroll
  for (int i = 0; i < 2; ++i) { f32x4 z = {0.f,0.f,0.f,0.f}; acc[i] = z; }

  const s16x4 zero4 = {0, 0, 0, 0};
  s16x4 pa[4];

#define GATH3(Q)                                                            \
  _Pragma("unroll") for (int i = 0; i < 4; ++i) {                           \
    int o = 2 * (Q) + (sc[i] >> 2);                                         \
    int ix = (o < KOFF) ? nbr[(size_t)(base + srow[i]) * KOFF + o] : -1;    \
    pa[i] = (ix >= 0)                                                       \
        ? *(const s16x4*)&x3dbf[(size_t)ix * C3 + (sc[i] & 3) * 4] : zero4; \
  }
#define WR3(B)                                                              \
  _Pragma("unroll") for (int i = 0; i < 4; ++i)                             \
    *(s16x4*)&fA[B][srow[i] * AS3 + (sc[i] >> 2) * 16 + (sc[i] & 3) * 4] = pa[i];

  GATH3(0)
  WR3(0)
  __syncthreads();

  for (int q = 0; q < QCH; ++q) {
    if (q + 1 < QCH) { GATH3(q + 1) }
    short8 af[2];
    #pragma unroll
    for (int i = 0; i < 2; ++i)
      af[i] = *(const short8*)&fA[q & 1][((w * 2 + i) * 16 + lm) * AS3 + quad * 8];
    short8 bfr = *(const short8*)&W3dF[(size_t)q * 512 + lane * 8];
    #pragma unroll
    for (int i = 0; i < 2; ++i)
      acc[i] = __builtin_amdgcn_mfma_f32_16x16x32_bf16(af[i], bfr, acc[i], 0, 0, 0);
    if (q + 1 < QCH) {
      WR3((q + 1) & 1)
      __syncthreads();
    }
  }
#undef GATH3
#undef WR3

  const int c = lm;
  const float g = g3d[c], b = b3d[c];
  #pragma unroll
  for (int i = 0; i < 2; ++i) {
    int rbase = base + (w * 2 + i) * 16 + quad * 4;
    #pragma unroll
    for (int rg = 0; rg < 4; ++rg) {
      int row = rbase + rg;
      float v = fmaxf(fmaf(acc[i][rg], g, b), 0.f);
      y3d[(size_t)row * C3 + c] = v;
      mix[(size_t)row * CM + c] = v;
      mixbf[(size_t)row * CM + c] = bf16r(v);
    }
  }
}

// ---------------------------------------------------------------------------
// Kernel 2: gate/cross fusion; phase-1 f2d gather software-pipelined.
// ---------------------------------------------------------------------------
__global__ __launch_bounds__(256) void gate_cross_mfma_kernel(
    const float* __restrict__ y3d, const float* __restrict__ f2d,
    const int* __restrict__ nn_idx,
    const float* __restrict__ Wg, const float* __restrict__ bg,
    const float* __restrict__ Wc, const float* __restrict__ bc,
    const short* __restrict__ WpF,
    short* __restrict__ p2dbf, float* __restrict__ cross2d)
{
  constexpr int RS = 296;
  __shared__ short g1S[32 * RS];
  __shared__ short g2S[32 * RS];
  const int tid = threadIdx.x;
  const int lane = tid & 63;
  const int w = tid >> 6;
  const int lm = lane & 15;
  const int quad = lane >> 4;
  const int base = blockIdx.x * 32;

  for (int e = tid; e < 32 * 32; e += 256) {
    int r = e >> 5, cc = 256 + (e & 31);
    if (cc >= CP) {
      g1S[r * RS + cc] = 0;
      g2S[r * RS + cc] = 0;
    }
  }

  {
    const int c = tid;
    float wg[16], wc[16];
    #pragma unroll
    for (int ci = 0; ci < 16; ++ci) {
      wg[ci] = Wg[ci * CP + c];
      wc[ci] = Wc[ci * CP + c];
    }
    const float bgv = bg[c], bcv = bc[c];
    int idx0 = nn_idx[base];
    float fnext = (idx0 >= 0) ? f2d[(size_t)idx0 * CP + c] : 0.f;
    for (int r = 0; r < 32; ++r) {
      float f = fnext;
      if (r + 1 < 32) {
        int idxn = nn_idx[base + r + 1];
        fnext = (idxn >= 0) ? f2d[(size_t)idxn * CP + c] : 0.f;
      }
      const float* yr = y3d + (size_t)(base + r) * C3;
      float a1 = bgv, a2 = bcv;
      #pragma unroll
      for (int ci = 0; ci < 16; ++ci) {
        float yv = yr[ci];
        a1 = fmaf(yv, wg[ci], a1);
        a2 = fmaf(yv, wc[ci], a2);
      }
      g1S[r * RS + c] = bf16r(fmaxf(a1, 0.f) * f);
      g2S[r * RS + c] = bf16r(fmaxf(a2, 0.f) * f);
    }
  }
  if (w == 0 && lane < 3) {
    const int c = 256 + lane;
    float wg[16], wc[16];
    #pragma unroll
    for (int ci = 0; ci < 16; ++ci) {
      wg[ci] = Wg[ci * CP + c];
      wc[ci] = Wc[ci * CP + c];
    }
    const float bgv = bg[c], bcv = bc[c];
    for (int r = 0; r < 32; ++r) {
      const int row = base + r;
      const int idx = nn_idx[row];
      const float* yr = y3d + (size_t)row * C3;
      float f = (idx >= 0) ? f2d[(size_t)idx * CP + c] : 0.f;
      float a1 = bgv, a2 = bcv;
      #pragma unroll
      for (int ci = 0; ci < 16; ++ci) {
        float yv = yr[ci];
        a1 = fmaf(yv, wg[ci], a1);
        a2 = fmaf(yv, wc[ci], a2);
      }
      g1S[r * RS + c] = bf16r(fmaxf(a1, 0.f) * f);
      g2S[r * RS + c] = bf16r(fmaxf(a2, 0.f) * f);
    }
  }
  __syncthreads();

  const int gsel = w & 1;
  const int mt = w >> 1;
  const short* gS = gsel ? g2S : g1S;
  f32x4 acc[4];
  #pragma unroll
  for (int t = 0; t < 4; ++t) { f32x4 z = {0.f,0.f,0.f,0.f}; acc[t] = z; }
  #pragma unroll
  for (int q = 0; q < 9; ++q) {
    short8 af = *(const short8*)&gS[(mt * 16 + lm) * RS + q * 32 + quad * 8];
    #pragma unroll
    for (int t = 0; t < 4; ++t) {
      short8 bf = *(const short8*)&WpF[(((q * 4 + t) * 64) + lane) * 8];
      acc[t] = __builtin_amdgcn_mfma_f32_16x16x32_bf16(af, bf, acc[t], 0, 0, 0);
    }
  }
  #pragma unroll
  for (int t = 0; t < 4; ++t) {
    const int c = t * 16 + lm;
    #pragma unroll
    for (int rg = 0; rg < 4; ++rg) {
      const int row = base + mt * 16 + quad * 4 + rg;
      float v = acc[t][rg];
      if (gsel == 0)
        p2dbf[(size_t)row * C2 + c] = bf16r(v);
      else
        cross2d[(size_t)row * C2 + c] = v;
    }
  }
}

// ---------------------------------------------------------------------------
// Double-buffered MFMA subm-conv with DISTANCE-2 pipeline, 1 barrier/k-iter.
// Invariants at top of iter k: buf[k&1]=tile k; pa[(k+1)&1]=tile k+1 (in
// flight); pidx[k&1]=indices for tile k+2 (in flight). Paired-iteration
// macro keeps register-array indices compile-time.
// MODE 0: bn_relu->fp32  1: bn_relu->bf16  2: relu(bn)+res64 -> mix+mixbf
// 3: relu(bn+res)->fp32+bf16  4: relu(bn+res)->bf16
// ---------------------------------------------------------------------------
template <int CIN, int COUT_, int MODE, int MINW>
__global__ __launch_bounds__(256, MINW) void conv_db_kernel(
    const short* __restrict__ finbf, const int* __restrict__ nbr, int nrows,
    const short* __restrict__ WbfF, const float* __restrict__ gamma,
    const float* __restrict__ beta, const float* __restrict__ resf,
    float* __restrict__ outf, short* __restrict__ outbf)
{
  constexpr int KC = (CIN + 31) / 32;
  constexpr int KC32 = KC * 32;
  constexpr int AS = KC32 + 8;
  constexpr int PCH = KC32 / 8;
  constexpr int DCH = CIN / 8;
  constexpr int NT = COUT_ / 16;
  constexpr int MT = 2;
  constexpr int ROWS = 128;
  constexpr int AR = ROWS * PCH / 256;

  __shared__ short fA[2][ROWS * AS];

  const int tid = threadIdx.x;
  const int lane = tid & 63;
  const int w = tid >> 6;
  const int lm = lane & 15;
  const int quad = lane >> 4;
  const int base = blockIdx.x * ROWS;

  int ar[AR], ac[AR], rw[AR];
  bool av[AR], rv[AR];
  #pragma unroll
  for (int i = 0; i < AR; ++i) {
    int j = tid + i * 256;
    ar[i] = j / PCH;
    ac[i] = j - ar[i] * PCH;
    av[i] = ac[i] < DCH;
    rw[i] = base + ar[i];
    rv[i] = rw[i] < nrows;
  }

  f32x4 acc[MT][NT];
  #pragma unroll
  for (int i = 0; i < MT; ++i)
    #pragma unroll
    for (int t = 0; t < NT; ++t) { f32x4 z = {0.f,0.f,0.f,0.f}; acc[i][t] = z; }

  const short8 zero8 = {0, 0, 0, 0, 0, 0, 0, 0};
  short8 pa[2][AR];
  int pidx[2][AR];

  // ---- prologue: buf0 <- tile0; pa[1] <- tile1; pidx[0] <- idx tile2 ----
  {
    int ix0[AR];
    #pragma unroll
    for (int i = 0; i < AR; ++i)
      ix0[i] = rv[i] ? nbr[(size_t)rw[i] * KOFF + 0] : -1;
    #pragma unroll
    for (int i = 0; i < AR; ++i)
      pidx[1][i] = rv[i] ? nbr[(size_t)rw[i] * KOFF + 1] : -1;
    #pragma unroll
    for (int i = 0; i < AR; ++i)
      pidx[0][i] = rv[i] ? nbr[(size_t)rw[i] * KOFF + 2] : -1;
    short8 t0[AR];
    #pragma unroll
    for (int i = 0; i < AR; ++i)
      t0[i] = (ix0[i] >= 0 && av[i])
          ? *(const short8*)&finbf[(size_t)ix0[i] * CIN + ac[i] * 8] : zero8;
    #pragma unroll
    for (int i = 0; i < AR; ++i) {
      int ix = pidx[1][i];
      pa[1][i] = (ix >= 0 && av[i])
          ? *(const short8*)&finbf[(size_t)ix * CIN + ac[i] * 8] : zero8;
    }
    #pragma unroll
    for (int i = 0; i < AR; ++i)
      *(short8*)&fA[0][ar[i] * AS + ac[i] * 8] = t0[i];
    __syncthreads();
  }

#define KITER(K, S)                                                             \
  {                                                                             \
    if ((K) + 3 < KOFF) {                                                       \
      _Pragma("unroll") for (int i = 0; i < AR; ++i)                            \
        pidx[S ^ 1][i] = rv[i] ? nbr[(size_t)rw[i] * KOFF + (K) + 3] : -1;      \
    }                                                                           \
    if ((K) + 2 < KOFF) {                                                       \
      _Pragma("unroll") for (int i = 0; i < AR; ++i) {                          \
        int ix = pidx[S][i];                                                    \
        pa[S][i] = (ix >= 0 && av[i])                                           \
            ? *(const short8*)&finbf[(size_t)ix * CIN + ac[i] * 8] : zero8;     \
      }                                                                         \
    }                                                                           \
    _Pragma("unroll") for (int q = 0; q < KC; ++q) {                            \
      short8 afr[MT];                                                           \
      _Pragma("unroll") for (int i = 0; i < MT; ++i)                            \
        afr[i] = *(const short8*)&fA[S][((w * MT + i) * 16 + lm) * AS +         \
                                        q * 32 + quad * 8];                     \
      _Pragma("unroll") for (int t = 0; t < NT; ++t) {                          \
        short8 bfr = *(const short8*)&WbfF[(size_t)((((K) * KC + q) * NT + t) * \
                                                    512) + lane * 8];           \
        _Pragma("unroll") for (int i = 0; i < MT; ++i)                          \
          acc[i][t] = __builtin_amdgcn_mfma_f32_16x16x32_bf16(afr[i], bfr,      \
                                                              acc[i][t], 0, 0, 0); \
      }                                                                         \
    }                                                                           \
    if ((K) + 1 < KOFF) {                                                       \
      _Pragma("unroll") for (int i = 0; i < AR; ++i)                            \
        *(short8*)&fA[S ^ 1][ar[i] * AS + ac[i] * 8] = pa[S ^ 1][i];            \
      __syncthreads();                                                          \
    }                                                                           \
  }

  for (int kk = 0; kk + 2 < KOFF; kk += 2) {
    KITER(kk, 0)
    KITER(kk + 1, 1)
  }
  KITER(KOFF - 1, 0)   // KOFF odd: last iter has parity 0
#undef KITER

  // ---- epilogue ----
  #pragma unroll
  for (int i = 0; i < MT; ++i) {
    int rbase = base + (w * MT + i) * 16 + quad * 4;
    #pragma unroll
    for (int t = 0; t < NT; ++t) {
      int c = t * 16 + lm;
      float g = gamma[c], b = beta[c];
      #pragma unroll
      for (int rg = 0; rg < 4; ++rg) {
        int row = rbase + rg;
        if (row >= nrows) continue;
        float v = acc[i][t][rg];
        if (MODE == 0) {
          outf[(size_t)row * COUT_ + c] = fmaxf(fmaf(v, g, b), 0.f);
        } else if (MODE == 1) {
          outbf[(size_t)row * COUT_ + c] = bf16r(fmaxf(fmaf(v, g, b), 0.f));
        } else if (MODE == 2) {
          float o = fmaxf(fmaf(v, g, b), 0.f) + resf[(size_t)row * C2 + c];
          outf[(size_t)row * CM + 16 + c] = o;
          outbf[(size_t)row * CM + 16 + c] = bf16r(o);
        } else if (MODE == 3) {
          float o = fmaxf(fmaf(v, g, b) + resf[(size_t)row * COUT_ + c], 0.f);
          outf[(size_t)row * COUT_ + c] = o;
          outbf[(size_t)row * COUT_ + c] = bf16r(o);
        } else {
          float o = fmaxf(fmaf(v, g, b) + resf[(size_t)row * COUT_ + c], 0.f);
          outbf[(size_t)row * COUT_ + c] = bf16r(o);
        }
      }
    }
  }
}

// ---------------------------------------------------------------------------
extern "C" void kernel_launch(void* const* d_in, const int* in_sizes, int n_in,
                              void* d_out, int out_size, void* d_ws, size_t ws_size,
                              hipStream_t stream) {
  const float* x3d  = (const float*)d_in[0];
  const float* f2d  = (const float*)d_in[1];
  const int*   nn   = (const int*)d_in[2];
  const int*   nbr  = (const int*)d_in[3];
  const int*   nbds = (const int*)d_in[4];
  const float* W3d  = (const float*)d_in[5];
  const float* g3d  = (const float*)d_in[6];
  const float* b3d  = (const float*)d_in[7];
  const float* Wg   = (const float*)d_in[8];
  const float* bg   = (const float*)d_in[9];
  const float* Wc   = (const float*)d_in[10];
  const float* bc   = (const float*)d_in[11];
  const float* Wp   = (const float*)d_in[12];
  const float* W2d  = (const float*)d_in[13];
  const float* g2d  = (const float*)d_in[14];
  const float* b2d  = (const float*)d_in[15];
  const float* Wm1  = (const float*)d_in[16];
  const float* gm1  = (const float*)d_in[17];
  const float* bm1  = (const float*)d_in[18];
  const float* Wm2  = (const float*)d_in[19];
  const float* gm2  = (const float*)d_in[20];
  const float* bm2  = (const float*)d_in[21];
  const float* Wa1  = (const float*)d_in[22];
  const float* ga1  = (const float*)d_in[23];
  const float* ba1  = (const float*)d_in[24];
  const float* Wa2  = (const float*)d_in[25];
  const float* ga2  = (const float*)d_in[26];
  const float* ba2  = (const float*)d_in[27];
  const float* Wds  = (const float*)d_in[28];
  const float* gds  = (const float*)d_in[29];
  const float* bds  = (const float*)d_in[30];

  const size_t N = NPTS;
  float* ws = (float*)d_ws;
  float* y3d     = ws;                    // N*16
  short* p2dbf   = (short*)(ws + N * 16); // N*64 bf16
  float* cross2d = ws + N * 48;           // N*64 (written by gate_cross)
  // x3dbf overlaps cross2d's region: x3dbf is consumed by conv3d BEFORE
  // gate_cross writes cross2d (stream-ordered) -> safe.
  short* x3dbf   = (short*)(ws + N * 48); // N*16 bf16 = N*8 floats
  float* mix     = ws + N * 112;          // N*80
  short* mixbf   = (short*)(ws + N * 192);// N*80 bf16
  short* tmp1bf  = (short*)(ws + N * 232);// N*80 bf16
  float* hbuf    = ws + N * 272;          // N*80
  short* hbufbf  = (short*)(ws + N * 352);// N*80 bf16
  short* abufbf  = (short*)ws;            // N*80 bf16 (reuses y3d+p2dbf)
  // fragment-ordered bf16 weights at tail
  short* wtail  = (short*)(ws + N * 392);
  short* WbfF2d = wtail;                   // 27*2*4*512 = 110592
  short* WbfFm1 = WbfF2d + 110592;         // 27*3*5*512 = 207360
  short* WbfFm2 = WbfFm1 + 207360;
  short* WbfFa1 = WbfFm2 + 207360;
  short* WbfFa2 = WbfFa1 + 207360;
  short* WbfFds = WbfFa2 + 207360;         // 27*3*6*512 = 248832
  short* WpF    = WbfFds + 248832;         // 18432
  short* W3dF   = WpF + 18432;             // 14*512 = 7168

  // ---- prep ----
  wfrag_kernel<<<(110592 + 255) / 256, 256, 0, stream>>>(W2d, WbfF2d, 64, 64, 2);
  wfrag_kernel<<<(207360 + 255) / 256, 256, 0, stream>>>(Wm1, WbfFm1, 80, 80, 3);
  wfrag_kernel<<<(207360 + 255) / 256, 256, 0, stream>>>(Wm2, WbfFm2, 80, 80, 3);
  wfrag_kernel<<<(207360 + 255) / 256, 256, 0, stream>>>(Wa1, WbfFa1, 80, 80, 3);
  wfrag_kernel<<<(207360 + 255) / 256, 256, 0, stream>>>(Wa2, WbfFa2, 80, 80, 3);
  wfrag_kernel<<<(248832 + 255) / 256, 256, 0, stream>>>(Wds, WbfFds, 80, 96, 3);
  wpfrag_kernel<<<(9 * 4 * 64 * 8 + 255) / 256, 256, 0, stream>>>(Wp, WpF);
  w3dfrag_kernel<<<(14 * 512 + 255) / 256, 256, 0, stream>>>(W3d, W3dF);
  x3dprep_kernel<<<(NPTS * C3 + 255) / 256, 256, 0, stream>>>(x3d, x3dbf);

  conv3d_mfma_kernel<<<NPTS / 128, 256, 0, stream>>>(x3dbf, nbr, W3dF, g3d, b3d,
                                                     y3d, mix, mixbf);
  gate_cross_mfma_kernel<<<NPTS / 32, 256, 0, stream>>>(y3d, f2d, nn, Wg, bg,
                                                        Wc, bc, WpF, p2dbf,
                                                        cross2d);

  const int gridN = (NPTS + 127) / 128;    // 625
  conv_db_kernel<64, 64, 2, 4><<<gridN, 256, 0, stream>>>(
      p2dbf, nbr, NPTS, WbfF2d, g2d, b2d, cross2d, mix, mixbf);
  conv_db_kernel<80, 80, 1, 3><<<gridN, 256, 0, stream>>>(
      mixbf, nbr, NPTS, WbfFm1, gm1, bm1, nullptr, nullptr, tmp1bf);
  conv_db_kernel<80, 80, 3, 3><<<gridN, 256, 0, stream>>>(
      tmp1bf, nbr, NPTS, WbfFm2, gm2, bm2, mix, hbuf, hbufbf);
  conv_db_kernel<80, 80, 1, 3><<<gridN, 256, 0, stream>>>(
      hbufbf, nbr, NPTS, WbfFa1, ga1, ba1, nullptr, nullptr, tmp1bf);
  conv_db_kernel<80, 80, 4, 3><<<gridN, 256, 0, stream>>>(
      tmp1bf, nbr, NPTS, WbfFa2, ga2, ba2, hbuf, nullptr, abufbf);

  const int gridND = (NDPTS + 127) / 128;  // 79
  conv_db_kernel<80, 96, 0, 3><<<gridND, 256, 0, stream>>>(
      abufbf, nbds, NDPTS, WbfFds, gds, bds, nullptr, (float*)d_out, nullptr);
}